// Round 7
// baseline (3055.708 us; speedup 1.0000x reference)
//
#include <hip/hip_runtime.h>
#include <stdint.h>

// Problem constants
#define VOCAB 50000
#define EMBD  128
#define HID   256
#define G4    1024   // 4*HID
#define BATCH 256
#define TSEQ  512
#define OUTD  64

typedef __attribute__((ext_vector_type(4))) float f32x4;
typedef __attribute__((ext_vector_type(8))) short short8;
typedef __attribute__((ext_vector_type(4))) unsigned short ushort4_t;

__device__ inline unsigned short f2bf(float f) {
  unsigned u = __float_as_uint(f);
  u += 0x7fffu + ((u >> 16) & 1u);     // round-nearest-even
  return (unsigned short)(u >> 16);
}
__device__ inline float bf2f(unsigned short u) {
  return __uint_as_float(((unsigned)u) << 16);
}
__device__ inline short8 pack2(f32x4 a, f32x4 b) {
  short8 r;
  r[0] = (short)f2bf(a[0]); r[1] = (short)f2bf(a[1]);
  r[2] = (short)f2bf(a[2]); r[3] = (short)f2bf(a[3]);
  r[4] = (short)f2bf(b[0]); r[5] = (short)f2bf(b[1]);
  r[6] = (short)f2bf(b[2]); r[7] = (short)f2bf(b[3]);
  return r;
}
__device__ inline float sigmoid_(float x) {
  return __builtin_amdgcn_rcpf(1.0f + __expf(-x));
}
__device__ inline float tanh_(float x) {
  float e = __expf(2.0f * x);
  return (e - 1.0f) * __builtin_amdgcn_rcpf(e + 1.0f);
}

// LDS-only barrier: h double-buffer needs only LDS ordering; global prefetch
// loads/stores stay in flight across it (R6 win, kept).
__device__ inline void barrier_lds_only() {
  asm volatile("s_waitcnt lgkmcnt(0)\n\ts_barrier" ::: "memory");
}

// Wx layout: Wx[v][u*4 + nt], u = h-unit 0..255, nt in {i,f,g,o}; oj = nt*256+u.

// ---------------------------------------------------------------------------
// K1: Wx[v][u*4+nt] = bf16( b_ih[oj] + b_hh[oj] + emb[v] . W_ih[oj] )
// ---------------------------------------------------------------------------
__global__ __launch_bounds__(256) void wx_k1(
    const float* __restrict__ emb, const float* __restrict__ Wih,
    const float* __restrict__ bih, const float* __restrict__ bhh,
    unsigned short* __restrict__ Wx) {
  const int vb = blockIdx.x * 16;
  const int w1 = threadIdx.x >> 6, lane = threadIdx.x & 63;
  const int quad = lane >> 4, n = lane & 15;
  const int combo = blockIdx.y * 4 + w1;        // 0..15 -> units combo*16..+15

  float bias[4];
  short8 bfr[4][4];
#pragma unroll
  for (int nt = 0; nt < 4; ++nt) {
    const int oj = nt * 256 + combo * 16 + n;
    bias[nt] = bih[oj] + bhh[oj];
#pragma unroll
    for (int kc = 0; kc < 4; ++kc) {
      const f32x4* wp = (const f32x4*)(Wih + (size_t)oj * EMBD + kc * 32 + quad * 8);
      bfr[nt][kc] = pack2(wp[0], wp[1]);
    }
  }
  short8 af[4];
#pragma unroll
  for (int kc = 0; kc < 4; ++kc) {
    const f32x4* ep = (const f32x4*)(emb + (size_t)(vb + n) * EMBD + kc * 32 + quad * 8);
    af[kc] = pack2(ep[0], ep[1]);
  }
  f32x4 acc[4];
#pragma unroll
  for (int nt = 0; nt < 4; ++nt) acc[nt] = (f32x4){0.f, 0.f, 0.f, 0.f};
#pragma unroll
  for (int kc = 0; kc < 4; ++kc)
#pragma unroll
    for (int nt = 0; nt < 4; ++nt)
      acc[nt] = __builtin_amdgcn_mfma_f32_16x16x32_bf16(af[kc], bfr[nt][kc], acc[nt], 0, 0, 0);
#pragma unroll
  for (int rr = 0; rr < 4; ++rr) {
    ushort4_t o;
#pragma unroll
    for (int nt = 0; nt < 4; ++nt) o[nt] = f2bf(acc[nt][rr] + bias[nt]);
    *(ushort4_t*)&Wx[(size_t)(vb + quad * 4 + rr) * G4 + (combo * 16 + n) * 4] = o;
  }
}

// ---------------------------------------------------------------------------
// K1b: pack W_hh K-chunks 6,7 into global B-frag order (coalesced dwordx4
// reads in K2; L2-resident 128 KB). tile = ((w*2+gl)*4+nt)*2+kcg.
// Wg[tile][lane][j] = bf16(Whh[nt*256+(2w+gl)*16+n][(6+kcg)*32+quad*8+j])
// ---------------------------------------------------------------------------
__global__ __launch_bounds__(256) void wg_k1b(
    const float* __restrict__ Whh, unsigned short* __restrict__ Wg) {
  const int tile = blockIdx.x * 4 + (threadIdx.x >> 6);   // 0..127
  const int lane = threadIdx.x & 63, quad = lane >> 4, n = lane & 15;
  const int kcg = tile & 1, nt = (tile >> 1) & 3, glw = tile >> 3;
  const int oj = nt * 256 + glw * 16 + n;
  const f32x4* wp = (const f32x4*)(Whh + (size_t)oj * HID + (6 + kcg) * 32 + quad * 8);
  *(short8*)&Wg[((size_t)tile * 64 + lane) * 8] = pack2(wp[0], wp[1]);
}

// ---------------------------------------------------------------------------
// K2: self-contained LSTM recurrence. 16 WGs x 512 threads; WG = 16 batch
// rows, ALL 256 h-units, one lgkm-only barrier/step.
// W_hh split: K-chunks 0..3 in VGPRs (128), 4..5 in LDS (128 KB), 6..7
// streamed from Wg (L2). The ~64 freed regs fund a[8] A-frag staging (read
// once, used by BOTH gl passes) and scheduler slack (R6 was at the 256-reg
// wall -> no prefetch hoisting). All register arrays constant-indexed.
// lastH written in-loop (exec-masked, rare); lgkm barrier doesn't drain it.
// ---------------------------------------------------------------------------
__global__ __launch_bounds__(512, 2) void lstm_k2(
    const int* __restrict__ x, const float* __restrict__ Whh,
    const unsigned short* __restrict__ Wx, const unsigned short* __restrict__ Wg,
    float* __restrict__ lastH) {               // [256][256]
  const int group = blockIdx.x;                // 16 groups of 16 batch rows
  const int rowbase = group * 16;
  const int tid = threadIdx.x;
  const int w = tid >> 6, lane = tid & 63;
  const int quad = lane >> 4, n = lane & 15;

  __shared__ __attribute__((aligned(16))) unsigned short h_lds[2][16][264];   // 16.5 KB
  __shared__ __attribute__((aligned(16))) unsigned short wlds[8][2][4][2][64][8]; // 128 KB
  __shared__ int zpos[16];

  if (tid < 16) zpos[tid] = 1 << 30;
  __syncthreads();
  for (int i = tid; i < 16 * TSEQ; i += 512) {
    const int row = i >> 9, tc = i & 511;
    if (x[(size_t)(rowbase + row) * TSEQ + tc] == 0) atomicMin(&zpos[row], tc);
  }
  for (int i = tid; i < 16 * 264; i += 512) ((unsigned short*)h_lds)[i] = 0;

  // LDS weights: K-chunks 4,5
#pragma unroll
  for (int gl = 0; gl < 2; ++gl)
#pragma unroll
    for (int nt = 0; nt < 4; ++nt)
#pragma unroll
      for (int kcl = 0; kcl < 2; ++kcl) {
        const int oj = nt * 256 + (2 * w + gl) * 16 + n;
        const f32x4* wp = (const f32x4*)(Whh + (size_t)oj * HID + (4 + kcl) * 32 + quad * 8);
        *(short8*)&wlds[w][gl][nt][kcl][lane][0] = pack2(wp[0], wp[1]);
      }

  // register weights: K-chunks 0..3
  short8 bfr[2][4][4];
#pragma unroll
  for (int gl = 0; gl < 2; ++gl)
#pragma unroll
    for (int nt = 0; nt < 4; ++nt) {
      const int oj = nt * 256 + (2 * w + gl) * 16 + n;
      const float* wrow = Whh + (size_t)oj * HID;
#pragma unroll
      for (int kc = 0; kc < 4; ++kc) {
        const f32x4* wp = (const f32x4*)(wrow + kc * 32 + quad * 8);
        bfr[gl][nt][kc] = pack2(wp[0], wp[1]);
      }
    }

  float cst[2][4];
#pragma unroll
  for (int gl = 0; gl < 2; ++gl)
#pragma unroll
    for (int rr = 0; rr < 4; ++rr) cst[gl][rr] = 0.f;

  __syncthreads();   // zpos, h(0), wlds ready
  int idx4[4];
#pragma unroll
  for (int rr = 0; rr < 4; ++rr) idx4[rr] = zpos[quad * 4 + rr] - 1;

  // per-gl Wg bases (loop-invariant)
  const unsigned short* wg0 = Wg + (size_t)((w * 2 + 0) * 4) * 2 * 64 * 8 + (size_t)lane * 8;
  const unsigned short* wg1 = Wg + (size_t)((w * 2 + 1) * 4) * 2 * 64 * 8 + (size_t)lane * 8;

  // initial Wx load (t=0) + token prefetch for t=1
  ushort4_t wxbuf[2][4];
  int tokc[4];
#pragma unroll
  for (int rr = 0; rr < 4; ++rr) {
    const int t0 = x[(size_t)(rowbase + quad * 4 + rr) * TSEQ + 0];
#pragma unroll
    for (int gl = 0; gl < 2; ++gl)
      wxbuf[gl][rr] = *(const ushort4_t*)(Wx + (size_t)t0 * G4 + ((2 * w + gl) * 16 + n) * 4);
    tokc[rr] = x[(size_t)(rowbase + quad * 4 + rr) * TSEQ + 1];
  }

  for (int t = 0; t < TSEQ; ++t) {
    const int p = t & 1, pn = p ^ 1;
    const int tnn = (t + 2 < TSEQ) ? (t + 2) : (TSEQ - 1);

    // ---- stage A-frags ONCE for both gl passes (8 b128; was 16 reads) ----
    short8 a[8];
#pragma unroll
    for (int kc = 0; kc < 8; ++kc)
      a[kc] = *(const short8*)&h_lds[p][n][kc * 32 + quad * 8];

    // ---- gl = 0 ----
    {
      // stream B chunks 6,7 from L2 (issued first -> latency under MFMAs)
      short8 g[8];
#pragma unroll
      for (int nt = 0; nt < 4; ++nt)
#pragma unroll
        for (int kcg = 0; kcg < 2; ++kcg)
          g[nt * 2 + kcg] = *(const short8*)(wg0 + (size_t)(nt * 2 + kcg) * 64 * 8);

      f32x4 acc[4];
#pragma unroll
      for (int rr = 0; rr < 4; ++rr) {
        const ushort4_t g4 = wxbuf[0][rr];
#pragma unroll
        for (int nt = 0; nt < 4; ++nt) acc[nt][rr] = bf2f(g4[nt]);
      }
      // re-issue Wx prefetch for t+1 (gl0 half)
#pragma unroll
      for (int rr = 0; rr < 4; ++rr)
        wxbuf[0][rr] = *(const ushort4_t*)(Wx + (size_t)tokc[rr] * G4 + ((2 * w + 0) * 16 + n) * 4);

#pragma unroll
      for (int kc = 0; kc < 4; ++kc)
#pragma unroll
        for (int nt = 0; nt < 4; ++nt)
          acc[nt] = __builtin_amdgcn_mfma_f32_16x16x32_bf16(a[kc], bfr[0][nt][kc], acc[nt], 0, 0, 0);
#pragma unroll
      for (int kcl = 0; kcl < 2; ++kcl)
#pragma unroll
        for (int nt = 0; nt < 4; ++nt) {
          const short8 b = *(const short8*)&wlds[w][0][nt][kcl][lane][0];
          acc[nt] = __builtin_amdgcn_mfma_f32_16x16x32_bf16(a[4 + kcl], b, acc[nt], 0, 0, 0);
        }
#pragma unroll
      for (int kcg = 0; kcg < 2; ++kcg)
#pragma unroll
        for (int nt = 0; nt < 4; ++nt)
          acc[nt] = __builtin_amdgcn_mfma_f32_16x16x32_bf16(a[6 + kcg], g[nt * 2 + kcg], acc[nt], 0, 0, 0);

      const int u = (2 * w + 0) * 16 + n;
#pragma unroll
      for (int rr = 0; rr < 4; ++rr) {
        const float gi = acc[0][rr], gf = acc[1][rr], gg = acc[2][rr], go = acc[3][rr];
        const float ci = sigmoid_(gf) * cst[0][rr] + sigmoid_(gi) * tanh_(gg);
        cst[0][rr] = ci;
        const float hv = sigmoid_(go) * tanh_(ci);
        h_lds[pn][quad * 4 + rr][u] = f2bf(hv);
        if (t == idx4[rr])
          lastH[(size_t)(rowbase + quad * 4 + rr) * HID + u] = hv;  // not drained by lgkm barrier
      }
    }

    // ---- gl = 1 ----
    {
      short8 g[8];
#pragma unroll
      for (int nt = 0; nt < 4; ++nt)
#pragma unroll
        for (int kcg = 0; kcg < 2; ++kcg)
          g[nt * 2 + kcg] = *(const short8*)(wg1 + (size_t)(nt * 2 + kcg) * 64 * 8);

      f32x4 acc[4];
#pragma unroll
      for (int rr = 0; rr < 4; ++rr) {
        const ushort4_t g4 = wxbuf[1][rr];
#pragma unroll
        for (int nt = 0; nt < 4; ++nt) acc[nt][rr] = bf2f(g4[nt]);
      }
#pragma unroll
      for (int rr = 0; rr < 4; ++rr)
        wxbuf[1][rr] = *(const ushort4_t*)(Wx + (size_t)tokc[rr] * G4 + ((2 * w + 1) * 16 + n) * 4);

#pragma unroll
      for (int kc = 0; kc < 4; ++kc)
#pragma unroll
        for (int nt = 0; nt < 4; ++nt)
          acc[nt] = __builtin_amdgcn_mfma_f32_16x16x32_bf16(a[kc], bfr[1][nt][kc], acc[nt], 0, 0, 0);
#pragma unroll
      for (int kcl = 0; kcl < 2; ++kcl)
#pragma unroll
        for (int nt = 0; nt < 4; ++nt) {
          const short8 b = *(const short8*)&wlds[w][1][nt][kcl][lane][0];
          acc[nt] = __builtin_amdgcn_mfma_f32_16x16x32_bf16(a[4 + kcl], b, acc[nt], 0, 0, 0);
        }
#pragma unroll
      for (int kcg = 0; kcg < 2; ++kcg)
#pragma unroll
        for (int nt = 0; nt < 4; ++nt)
          acc[nt] = __builtin_amdgcn_mfma_f32_16x16x32_bf16(a[6 + kcg], g[nt * 2 + kcg], acc[nt], 0, 0, 0);

      const int u = (2 * w + 1) * 16 + n;
#pragma unroll
      for (int rr = 0; rr < 4; ++rr) {
        const float gi = acc[0][rr], gf = acc[1][rr], gg = acc[2][rr], go = acc[3][rr];
        const float ci = sigmoid_(gf) * cst[1][rr] + sigmoid_(gi) * tanh_(gg);
        cst[1][rr] = ci;
        const float hv = sigmoid_(go) * tanh_(ci);
        h_lds[pn][quad * 4 + rr][u] = f2bf(hv);
        if (t == idx4[rr])
          lastH[(size_t)(rowbase + quad * 4 + rr) * HID + u] = hv;
      }
    }

    // token prefetch for t+2
#pragma unroll
    for (int rr = 0; rr < 4; ++rr)
      tokc[rr] = x[(size_t)(rowbase + quad * 4 + rr) * TSEQ + tnn];

    barrier_lds_only();  // h(t+1) complete; global prefetches stay in flight
  }
}

// ---------------------------------------------------------------------------
// K3: logits + softmax. One wave per batch row; lane j = output j.
// ---------------------------------------------------------------------------
__global__ __launch_bounds__(64) void head_k3(
    const float* __restrict__ lastH, const float* __restrict__ Wout,
    const float* __restrict__ bout, float* __restrict__ out) {
  const int b = blockIdx.x, j = threadIdx.x;
  const f32x4* hv = (const f32x4*)(lastH + (size_t)b * HID);
  const f32x4* wv = (const f32x4*)(Wout + (size_t)j * HID);
  float acc = bout[j];
#pragma unroll 8
  for (int k = 0; k < HID / 4; ++k) {
    const f32x4 a = hv[k], ww = wv[k];
    acc += a[0] * ww[0] + a[1] * ww[1] + a[2] * ww[2] + a[3] * ww[3];
  }
  float m = acc;
  for (int s = 32; s > 0; s >>= 1) m = fmaxf(m, __shfl_xor(m, s, 64));
  const float e = __expf(acc - m);
  float ssum = e;
  for (int s = 32; s > 0; s >>= 1) ssum += __shfl_xor(ssum, s, 64);
  out[(size_t)b * OUTD + j] = e / ssum;
}

// ---------------------------------------------------------------------------
extern "C" void kernel_launch(void* const* d_in, const int* in_sizes, int n_in,
                              void* d_out, int out_size, void* d_ws, size_t ws_size,
                              hipStream_t stream) {
  const int*   x    = (const int*)d_in[0];
  const float* emb  = (const float*)d_in[1];
  const float* Wih  = (const float*)d_in[2];
  const float* Whh  = (const float*)d_in[3];
  const float* bih  = (const float*)d_in[4];
  const float* bhh  = (const float*)d_in[5];
  const float* Wout = (const float*)d_in[6];
  const float* bout = (const float*)d_in[7];
  float* out = (float*)d_out;

  // workspace carve (~98.1 MiB)
  char* ws = (char*)d_ws;
  unsigned short* Wx = (unsigned short*)ws;                 // 102,400,000 B
  unsigned short* Wg = (unsigned short*)(ws + 102400000);   // 131,072 B
  float* lastH = (float*)(ws + 102400000 + 131072);         // 262,144 B

  hipLaunchKernelGGL(wx_k1, dim3(3125, 4), dim3(256), 0, stream,
                     emb, Wih, bih, bhh, Wx);
  hipLaunchKernelGGL(wg_k1b, dim3(32), dim3(256), 0, stream, Whh, Wg);
  hipLaunchKernelGGL(lstm_k2, dim3(16), dim3(512), 0, stream,
                     x, Whh, Wx, Wg, lastH);
  hipLaunchKernelGGL(head_k3, dim3(BATCH), dim3(OUTD), 0, stream,
                     lastH, Wout, bout, out);
}

// Round 8
// 2328.065 us; speedup vs baseline: 1.3126x; 1.3126x over previous
//
#include <hip/hip_runtime.h>
#include <stdint.h>

// Problem constants
#define VOCAB 50000
#define EMBD  128
#define HID   256
#define G4    1024   // 4*HID
#define BATCH 256
#define TSEQ  512
#define OUTD  64

typedef __attribute__((ext_vector_type(4))) float f32x4;
typedef __attribute__((ext_vector_type(8))) short short8;
typedef __attribute__((ext_vector_type(4))) unsigned short ushort4_t;
typedef __attribute__((ext_vector_type(8))) unsigned short ushort8_t;

__device__ inline unsigned short f2bf(float f) {
  unsigned u = __float_as_uint(f);
  u += 0x7fffu + ((u >> 16) & 1u);     // round-nearest-even
  return (unsigned short)(u >> 16);
}
__device__ inline float bf2f(unsigned short u) {
  return __uint_as_float(((unsigned)u) << 16);
}
__device__ inline short8 pack2(f32x4 a, f32x4 b) {
  short8 r;
  r[0] = (short)f2bf(a[0]); r[1] = (short)f2bf(a[1]);
  r[2] = (short)f2bf(a[2]); r[3] = (short)f2bf(a[3]);
  r[4] = (short)f2bf(b[0]); r[5] = (short)f2bf(b[1]);
  r[6] = (short)f2bf(b[2]); r[7] = (short)f2bf(b[3]);
  return r;
}

// LDS-only barrier (R6 win): h double-buffer needs only LDS ordering; global
// prefetch loads stay in flight across it. NOTE (R7 lesson): any global load
// consumed in the SAME step gets a conservative compiler vmcnt wait that
// drains the prefetch queue -> only cross-step-consumed loads are allowed.
__device__ inline void barrier_lds_only() {
  asm volatile("s_waitcnt lgkmcnt(0)\n\ts_barrier" ::: "memory");
}

// Wx layout: Wx[v][u*4 + nt], u = h-unit 0..255, nt in {i,f,g,o}; oj = nt*256+u.
// K2 unit ownership (interleaved): lane (w,quad,n) owns units w*32+2n (gl0)
// and w*32+2n+1 (gl1) -> one 16B Wx load covers both; h-writes pack to b32.

// ---------------------------------------------------------------------------
// K1: Wx[v][u*4+nt] = bf16( b_ih[oj] + b_hh[oj] + emb[v] . W_ih[oj] )
// ---------------------------------------------------------------------------
__global__ __launch_bounds__(256) void wx_k1(
    const float* __restrict__ emb, const float* __restrict__ Wih,
    const float* __restrict__ bih, const float* __restrict__ bhh,
    unsigned short* __restrict__ Wx) {
  const int vb = blockIdx.x * 16;
  const int w1 = threadIdx.x >> 6, lane = threadIdx.x & 63;
  const int quad = lane >> 4, n = lane & 15;
  const int combo = blockIdx.y * 4 + w1;        // 0..15 -> units combo*16..+15

  float bias[4];
  short8 bfr[4][4];
#pragma unroll
  for (int nt = 0; nt < 4; ++nt) {
    const int oj = nt * 256 + combo * 16 + n;
    bias[nt] = bih[oj] + bhh[oj];
#pragma unroll
    for (int kc = 0; kc < 4; ++kc) {
      const f32x4* wp = (const f32x4*)(Wih + (size_t)oj * EMBD + kc * 32 + quad * 8);
      bfr[nt][kc] = pack2(wp[0], wp[1]);
    }
  }
  short8 af[4];
#pragma unroll
  for (int kc = 0; kc < 4; ++kc) {
    const f32x4* ep = (const f32x4*)(emb + (size_t)(vb + n) * EMBD + kc * 32 + quad * 8);
    af[kc] = pack2(ep[0], ep[1]);
  }
  f32x4 acc[4];
#pragma unroll
  for (int nt = 0; nt < 4; ++nt) acc[nt] = (f32x4){0.f, 0.f, 0.f, 0.f};
#pragma unroll
  for (int kc = 0; kc < 4; ++kc)
#pragma unroll
    for (int nt = 0; nt < 4; ++nt)
      acc[nt] = __builtin_amdgcn_mfma_f32_16x16x32_bf16(af[kc], bfr[nt][kc], acc[nt], 0, 0, 0);
#pragma unroll
  for (int rr = 0; rr < 4; ++rr) {
    ushort4_t o;
#pragma unroll
    for (int nt = 0; nt < 4; ++nt) o[nt] = f2bf(acc[nt][rr] + bias[nt]);
    *(ushort4_t*)&Wx[(size_t)(vb + quad * 4 + rr) * G4 + (combo * 16 + n) * 4] = o;
  }
}

// ---------------------------------------------------------------------------
// K2: self-contained LSTM recurrence (R6 structure). 16 WGs x 512 threads;
// WG = 16 batch rows, ALL 256 h-units, one lgkm-only barrier/step.
// W_hh: K-chunks 0..5 in VGPRs (192/lane), 6..7 in LDS (128 KB).
// Register arrays constant-indexed only (R1 lesson). No same-step global
// consumption (R7 lesson). Unrolled x2 so ping-pong index is constant.
// ---------------------------------------------------------------------------
__global__ __launch_bounds__(512, 2) void lstm_k2(
    const int* __restrict__ x, const float* __restrict__ Whh,
    const unsigned short* __restrict__ Wx,
    float* __restrict__ lastH) {               // [256][256]
  const int group = blockIdx.x;                // 16 groups of 16 batch rows
  const int rowbase = group * 16;
  const int tid = threadIdx.x;
  const int w = tid >> 6, lane = tid & 63;
  const int quad = lane >> 4, n = lane & 15;
  const int ub = w * 32 + 2 * n;               // unit pair base (gl adds 0/1)

  __shared__ __attribute__((aligned(16))) unsigned short h_lds[2][16][264];   // 16.5 KB
  __shared__ __attribute__((aligned(16))) unsigned short wlds[8][2][4][2][64][8]; // 128 KB
  __shared__ int zpos[16];

  if (tid < 16) zpos[tid] = 1 << 30;
  __syncthreads();
  for (int i = tid; i < 16 * TSEQ; i += 512) {
    const int row = i >> 9, tc = i & 511;
    if (x[(size_t)(rowbase + row) * TSEQ + tc] == 0) atomicMin(&zpos[row], tc);
  }
  for (int i = tid; i < 16 * 264; i += 512) ((unsigned short*)h_lds)[i] = 0;

  // LDS weights: K-chunks 6,7 (B-frag layout, interleaved unit mapping)
#pragma unroll
  for (int gl = 0; gl < 2; ++gl)
#pragma unroll
    for (int nt = 0; nt < 4; ++nt)
#pragma unroll
      for (int kcl = 0; kcl < 2; ++kcl) {
        const int oj = nt * 256 + ub + gl;
        const f32x4* wp = (const f32x4*)(Whh + (size_t)oj * HID + (6 + kcl) * 32 + quad * 8);
        *(short8*)&wlds[w][gl][nt][kcl][lane][0] = pack2(wp[0], wp[1]);
      }

  // register weights: K-chunks 0..5
  short8 bfr0[4][6], bfr1[4][6];
#pragma unroll
  for (int nt = 0; nt < 4; ++nt) {
    const float* wr0 = Whh + (size_t)(nt * 256 + ub) * HID;
    const float* wr1 = Whh + (size_t)(nt * 256 + ub + 1) * HID;
#pragma unroll
    for (int kc = 0; kc < 6; ++kc) {
      const f32x4* wp0 = (const f32x4*)(wr0 + kc * 32 + quad * 8);
      bfr0[nt][kc] = pack2(wp0[0], wp0[1]);
      const f32x4* wp1 = (const f32x4*)(wr1 + kc * 32 + quad * 8);
      bfr1[nt][kc] = pack2(wp1[0], wp1[1]);
    }
  }

  float cst0[4], cst1[4], last0[4], last1[4];
#pragma unroll
  for (int rr = 0; rr < 4; ++rr) {
    cst0[rr] = 0.f; cst1[rr] = 0.f; last0[rr] = 0.f; last1[rr] = 0.f;
  }

  __syncthreads();   // zpos, h(0), wlds ready
  int idx4[4];
#pragma unroll
  for (int rr = 0; rr < 4; ++rr) idx4[rr] = zpos[quad * 4 + rr] - 1;

  // initial Wx load (t=0, both units in one 16B load) + token prefetch (t=1)
  ushort8_t wxbuf[4];
  int tokc[4];
#pragma unroll
  for (int rr = 0; rr < 4; ++rr) {
    const int t0 = x[(size_t)(rowbase + quad * 4 + rr) * TSEQ + 0];
    wxbuf[rr] = *(const ushort8_t*)(Wx + (size_t)t0 * G4 + ub * 4);
    tokc[rr] = x[(size_t)(rowbase + quad * 4 + rr) * TSEQ + 1];
  }

  // fused LSTM pointwise: 5 exp + 3 rcp (vs naive 5+5)
  //   c' = c*rcp(1+e^-f) + (e^{2g}-1)*rcp((1+e^-i)(e^{2g}+1))
  //   h  = (e^{2c'}-1)*rcp((1+e^-o)(e^{2c'}+1))
  auto step = [&](int t, int p, int pn) {
    // split the prefetched Wx (gl0 = units ub, gl1 = ub+1), then re-issue
    ushort4_t lo[4], hi[4];
#pragma unroll
    for (int rr = 0; rr < 4; ++rr) {
      lo[rr][0] = wxbuf[rr][0]; lo[rr][1] = wxbuf[rr][1];
      lo[rr][2] = wxbuf[rr][2]; lo[rr][3] = wxbuf[rr][3];
      hi[rr][0] = wxbuf[rr][4]; hi[rr][1] = wxbuf[rr][5];
      hi[rr][2] = wxbuf[rr][6]; hi[rr][3] = wxbuf[rr][7];
    }
#pragma unroll
    for (int rr = 0; rr < 4; ++rr)
      wxbuf[rr] = *(const ushort8_t*)(Wx + (size_t)tokc[rr] * G4 + ub * 4);   // for t+1
    {
      const int tnn = (t + 2 < TSEQ) ? (t + 2) : (TSEQ - 1);
#pragma unroll
      for (int rr = 0; rr < 4; ++rr)
        tokc[rr] = x[(size_t)(rowbase + quad * 4 + rr) * TSEQ + tnn];          // for t+2
    }

    unsigned short h0[4], h1[4];

    // ---- gl = 0 ----
    {
      f32x4 acc[4];
#pragma unroll
      for (int rr = 0; rr < 4; ++rr)
#pragma unroll
        for (int nt = 0; nt < 4; ++nt) acc[nt][rr] = bf2f(lo[rr][nt]);
#pragma unroll
      for (int kc = 0; kc < 6; ++kc) {
        const short8 a = *(const short8*)&h_lds[p][n][kc * 32 + quad * 8];
#pragma unroll
        for (int nt = 0; nt < 4; ++nt)
          acc[nt] = __builtin_amdgcn_mfma_f32_16x16x32_bf16(a, bfr0[nt][kc], acc[nt], 0, 0, 0);
      }
#pragma unroll
      for (int kcl = 0; kcl < 2; ++kcl) {
        const short8 a = *(const short8*)&h_lds[p][n][(6 + kcl) * 32 + quad * 8];
#pragma unroll
        for (int nt = 0; nt < 4; ++nt) {
          const short8 b = *(const short8*)&wlds[w][0][nt][kcl][lane][0];
          acc[nt] = __builtin_amdgcn_mfma_f32_16x16x32_bf16(a, b, acc[nt], 0, 0, 0);
        }
      }
#pragma unroll
      for (int rr = 0; rr < 4; ++rr) {
        const float ei = __expf(-acc[0][rr]), ef = __expf(-acc[1][rr]);
        const float eg2 = __expf(2.0f * acc[2][rr]), eo = __expf(-acc[3][rr]);
        const float r1 = __builtin_amdgcn_rcpf(1.0f + ef);
        const float r2 = __builtin_amdgcn_rcpf((1.0f + ei) * (eg2 + 1.0f));
        const float c = cst0[rr] * r1 + (eg2 - 1.0f) * r2;
        cst0[rr] = c;
        const float ec2 = __expf(2.0f * c);
        const float r3 = __builtin_amdgcn_rcpf((1.0f + eo) * (ec2 + 1.0f));
        const float hv = (ec2 - 1.0f) * r3;
        last0[rr] = (t == idx4[rr]) ? hv : last0[rr];
        h0[rr] = f2bf(hv);
      }
    }
    // ---- gl = 1 ----
    {
      f32x4 acc[4];
#pragma unroll
      for (int rr = 0; rr < 4; ++rr)
#pragma unroll
        for (int nt = 0; nt < 4; ++nt) acc[nt][rr] = bf2f(hi[rr][nt]);
#pragma unroll
      for (int kc = 0; kc < 6; ++kc) {
        const short8 a = *(const short8*)&h_lds[p][n][kc * 32 + quad * 8];
#pragma unroll
        for (int nt = 0; nt < 4; ++nt)
          acc[nt] = __builtin_amdgcn_mfma_f32_16x16x32_bf16(a, bfr1[nt][kc], acc[nt], 0, 0, 0);
      }
#pragma unroll
      for (int kcl = 0; kcl < 2; ++kcl) {
        const short8 a = *(const short8*)&h_lds[p][n][(6 + kcl) * 32 + quad * 8];
#pragma unroll
        for (int nt = 0; nt < 4; ++nt) {
          const short8 b = *(const short8*)&wlds[w][1][nt][kcl][lane][0];
          acc[nt] = __builtin_amdgcn_mfma_f32_16x16x32_bf16(a, b, acc[nt], 0, 0, 0);
        }
      }
#pragma unroll
      for (int rr = 0; rr < 4; ++rr) {
        const float ei = __expf(-acc[0][rr]), ef = __expf(-acc[1][rr]);
        const float eg2 = __expf(2.0f * acc[2][rr]), eo = __expf(-acc[3][rr]);
        const float r1 = __builtin_amdgcn_rcpf(1.0f + ef);
        const float r2 = __builtin_amdgcn_rcpf((1.0f + ei) * (eg2 + 1.0f));
        const float c = cst1[rr] * r1 + (eg2 - 1.0f) * r2;
        cst1[rr] = c;
        const float ec2 = __expf(2.0f * c);
        const float r3 = __builtin_amdgcn_rcpf((1.0f + eo) * (ec2 + 1.0f));
        const float hv = (ec2 - 1.0f) * r3;
        last1[rr] = (t == idx4[rr]) ? hv : last1[rr];
        h1[rr] = f2bf(hv);
      }
    }

    // packed h-write: both units in one b32 (ub even -> 4B aligned)
#pragma unroll
    for (int rr = 0; rr < 4; ++rr) {
      const unsigned pv = (unsigned)h0[rr] | ((unsigned)h1[rr] << 16);
      *(unsigned*)&h_lds[pn][quad * 4 + rr][ub] = pv;
    }

    barrier_lds_only();  // h(t+1) complete; global prefetches stay in flight
  };

  for (int t2 = 0; t2 < TSEQ; t2 += 2) {
    step(t2, 0, 1);
    step(t2 + 1, 1, 0);
  }

  // final: write gathered last-valid h (f32, pre-bf16-rounding)
#pragma unroll
  for (int rr = 0; rr < 4; ++rr) {
    float* dst = lastH + (size_t)(rowbase + quad * 4 + rr) * HID + ub;
    dst[0] = last0[rr];
    dst[1] = last1[rr];
  }
}

// ---------------------------------------------------------------------------
// K3: logits + softmax. One wave per batch row; lane j = output j.
// ---------------------------------------------------------------------------
__global__ __launch_bounds__(64) void head_k3(
    const float* __restrict__ lastH, const float* __restrict__ Wout,
    const float* __restrict__ bout, float* __restrict__ out) {
  const int b = blockIdx.x, j = threadIdx.x;
  const f32x4* hv = (const f32x4*)(lastH + (size_t)b * HID);
  const f32x4* wv = (const f32x4*)(Wout + (size_t)j * HID);
  float acc = bout[j];
#pragma unroll 8
  for (int k = 0; k < HID / 4; ++k) {
    const f32x4 a = hv[k], ww = wv[k];
    acc += a[0] * ww[0] + a[1] * ww[1] + a[2] * ww[2] + a[3] * ww[3];
  }
  float m = acc;
  for (int s = 32; s > 0; s >>= 1) m = fmaxf(m, __shfl_xor(m, s, 64));
  const float e = __expf(acc - m);
  float ssum = e;
  for (int s = 32; s > 0; s >>= 1) ssum += __shfl_xor(ssum, s, 64);
  out[(size_t)b * OUTD + j] = e / ssum;
}

// ---------------------------------------------------------------------------
extern "C" void kernel_launch(void* const* d_in, const int* in_sizes, int n_in,
                              void* d_out, int out_size, void* d_ws, size_t ws_size,
                              hipStream_t stream) {
  const int*   x    = (const int*)d_in[0];
  const float* emb  = (const float*)d_in[1];
  const float* Wih  = (const float*)d_in[2];
  const float* Whh  = (const float*)d_in[3];
  const float* bih  = (const float*)d_in[4];
  const float* bhh  = (const float*)d_in[5];
  const float* Wout = (const float*)d_in[6];
  const float* bout = (const float*)d_in[7];
  float* out = (float*)d_out;

  // workspace carve (~97.9 MiB)
  char* ws = (char*)d_ws;
  unsigned short* Wx = (unsigned short*)ws;                 // 102,400,000 B
  float* lastH = (float*)(ws + 102400000);                  // 262,144 B

  hipLaunchKernelGGL(wx_k1, dim3(3125, 4), dim3(256), 0, stream,
                     emb, Wih, bih, bhh, Wx);
  hipLaunchKernelGGL(lstm_k2, dim3(16), dim3(512), 0, stream,
                     x, Whh, Wx, lastH);
  hipLaunchKernelGGL(head_k3, dim3(BATCH), dim3(OUTD), 0, stream,
                     lastH, Wout, bout, out);
}